// Round 6
// baseline (22247.801 us; speedup 1.0000x reference)
//
#include <hip/hip_runtime.h>
#include <hip/hip_bf16.h>

typedef float v4f __attribute__((ext_vector_type(4)));
typedef int   v4i __attribute__((ext_vector_type(4)));

#define T_LEN 8192
#define E_DIM 1024
#define HD    512
#define G4    2048
#define K_TAGS 34

// ---------------- ws layout (bytes) ----------------
#define XP_OFF      0ull                  // 2 * 8192 * 2048 f32 = 128MB
#define HS_OFF      134217728ull          // 2 * 8192 * 512 f32  = 32MB
#define FEATS_OFF   167772160ull          // 8192*34 f32
#define BP_OFF      168886272ull          // 8192*34 u8
#define BEST_OFF    169165824ull          // int

// =========================================================
// xp GEMM: xp[dir][t][r] = sentence[t] . w_ih[dir][r] + b_ih[r]+b_hh[r]
// =========================================================
#define BM 128
#define BN 128
#define BKK 16

__global__ __launch_bounds__(256) void xp_gemm(
    const float* __restrict__ A, const float* __restrict__ Wf, const float* __restrict__ Wb,
    const float* __restrict__ bihf, const float* __restrict__ bhhf,
    const float* __restrict__ bihb, const float* __restrict__ bhhb,
    float* __restrict__ xp)
{
  __shared__ __align__(16) float a_lds[BKK][BM + 4];
  __shared__ __align__(16) float b_lds[BKK][BN + 4];
  const int dir = blockIdx.z;
  const float* W   = dir ? Wb : Wf;
  const float* bih = dir ? bihb : bihf;
  const float* bhh = dir ? bhhb : bhhf;
  const int tid = threadIdx.x;
  const int srow = tid >> 1, sh = (tid & 1) * 8;
  const int tx = tid & 15, ty = tid >> 4;
  const size_t arow = (size_t)(blockIdx.x * BM + srow) * E_DIM;
  const size_t brow = (size_t)(blockIdx.y * BN + srow) * E_DIM;
  float acc[8][8];
  #pragma unroll
  for (int i = 0; i < 8; ++i)
    #pragma unroll
    for (int j = 0; j < 8; ++j) acc[i][j] = 0.f;

  for (int k0 = 0; k0 < E_DIM; k0 += BKK) {
    v4f a0 = *(const v4f*)(A + arow + k0 + sh);
    v4f a1 = *(const v4f*)(A + arow + k0 + sh + 4);
    v4f b0 = *(const v4f*)(W + brow + k0 + sh);
    v4f b1 = *(const v4f*)(W + brow + k0 + sh + 4);
    __syncthreads();
    #pragma unroll
    for (int j = 0; j < 4; ++j) {
      a_lds[sh + j][srow]     = a0[j];
      a_lds[sh + 4 + j][srow] = a1[j];
      b_lds[sh + j][srow]     = b0[j];
      b_lds[sh + 4 + j][srow] = b1[j];
    }
    __syncthreads();
    #pragma unroll
    for (int kk = 0; kk < BKK; ++kk) {
      v4f av0 = *(const v4f*)&a_lds[kk][ty * 8];
      v4f av1 = *(const v4f*)&a_lds[kk][ty * 8 + 4];
      v4f bv0 = *(const v4f*)&b_lds[kk][tx * 4];
      v4f bv1 = *(const v4f*)&b_lds[kk][64 + tx * 4];
      float av[8] = {av0[0],av0[1],av0[2],av0[3],av1[0],av1[1],av1[2],av1[3]};
      float bv[8] = {bv0[0],bv0[1],bv0[2],bv0[3],bv1[0],bv1[1],bv1[2],bv1[3]};
      #pragma unroll
      for (int i = 0; i < 8; ++i)
        #pragma unroll
        for (int j = 0; j < 8; ++j) acc[i][j] = fmaf(av[i], bv[j], acc[i][j]);
    }
  }
  const int gm  = blockIdx.x * BM + ty * 8;
  const int gnl = blockIdx.y * BN + tx * 4;
  const int gnh = gnl + 64;
  float bias[8];
  #pragma unroll
  for (int j = 0; j < 4; ++j) bias[j]     = bih[gnl + j] + bhh[gnl + j];
  #pragma unroll
  for (int j = 0; j < 4; ++j) bias[4 + j] = bih[gnh + j] + bhh[gnh + j];
  float* outp = xp + ((size_t)dir * T_LEN) * G4;
  #pragma unroll
  for (int i = 0; i < 8; ++i) {
    v4f o0 = {acc[i][0]+bias[0], acc[i][1]+bias[1], acc[i][2]+bias[2], acc[i][3]+bias[3]};
    v4f o1 = {acc[i][4]+bias[4], acc[i][5]+bias[5], acc[i][6]+bias[6], acc[i][7]+bias[7]};
    *(v4f*)(outp + (size_t)(gm + i) * G4 + gnl) = o0;
    *(v4f*)(outp + (size_t)(gm + i) * G4 + gnh) = o1;
  }
}

// =========================================================
// Persistent BiLSTM recurrence. 64 blocks (32/dir) x 1024 threads.
//  - waves 14,15: poll full h row (sentinel, sc0 sc1), publish to LDS hl
//    + LDS ready flag (hang-proof: pollers never wait on the block).
//  - waves 0..13: spin on LDS flag instead of polling L3 (8x less L3
//    poll traffic than all-wave polling).
//  - wave w computes all 4 gate rows of unit w fully IN-WAVE (DPP tree
//    + ordered shfl sum) -> gt[s&1][gate][unit]; ONE barrier per step.
//  - tail computed redundantly by every wave (no 2nd barrier, no
//    straggler); wave0 lanes<16 store h (one coalesced 64B, sc0 sc1).
// All sum orders bit-identical to the round-2/4 passing kernels.
// =========================================================
__device__ __forceinline__ float row16_sum(float x) {
  x += __int_as_float(__builtin_amdgcn_update_dpp(0, __float_as_int(x), 0x111, 0xf, 0xf, true));
  x += __int_as_float(__builtin_amdgcn_update_dpp(0, __float_as_int(x), 0x112, 0xf, 0xf, true));
  x += __int_as_float(__builtin_amdgcn_update_dpp(0, __float_as_int(x), 0x114, 0xf, 0xf, true));
  x += __int_as_float(__builtin_amdgcn_update_dpp(0, __float_as_int(x), 0x118, 0xf, 0xf, true));
  return x; // lane (16q+15) holds sum of its 16-lane group
}

__device__ __forceinline__ float sigmoidf_(float x) { return 1.f / (1.f + expf(-x)); }

__global__ __launch_bounds__(1024) void lstm_kernel(
    const float* __restrict__ h0, const float* __restrict__ c0,
    const float* __restrict__ whhf, const float* __restrict__ whhb,
    const float* __restrict__ xp, float* __restrict__ hs)
{
  const int b = blockIdx.x;
  const int dir = b >> 5, bb = b & 31;
  const int tid = threadIdx.x;
  const int w = tid >> 6, L = tid & 63;
  const float* whh = dir ? whhb : whhf;
  const float* xpd = xp + (size_t)dir * T_LEN * G4;
  float* hsd = hs + (size_t)dir * T_LEN * HD;

  __shared__ __align__(16) float hl[2][HD];
  __shared__ float gt[2][4][16];
  volatile __shared__ int hrdy[2];

  // wave w owns unit (bb*16 + w): gate rows g*HD + bb*16 + w, g=0..3
  float wreg[4][8];
  #pragma unroll
  for (int g = 0; g < 4; ++g) {
    const int grow = g * HD + bb * 16 + w;
    const float* p = whh + (size_t)grow * HD + 8 * L;
    v4f q0 = *(const v4f*)p;
    v4f q1 = *(const v4f*)(p + 4);
    #pragma unroll
    for (int kk = 0; kk < 4; ++kk) { wreg[g][kk] = q0[kk]; wreg[g][4 + kk] = q1[kk]; }
  }
  // redundant tail state: every wave's lanes<16 carry c for unit (bb*16+L)
  float cst = (L < 16) ? c0[dir * HD + bb * 16 + L] : 0.f;
  // per-lane xp prefetch: lane L handles gate row g=L>>4, unit u=L&15
  const int xcol = (L >> 4) * HD + bb * 16 + (L & 15);
  float xpc = xpd[(size_t)(dir ? (T_LEN - 1) : 0) * G4 + xcol];

  if (tid == 0) { hrdy[0] = 0; hrdy[1] = 0; }
  __syncthreads();

  for (int s = 0; s < T_LEN; ++s) {
    const int t = dir ? (T_LEN - 1 - s) : s;
    const int sl = s & 1;

    float hr[8];
    if (s == 0) {
      const float* hp = h0 + dir * HD + 8 * L;
      v4f a = *(const v4f*)hp;
      v4f bq = *(const v4f*)(hp + 4);
      #pragma unroll
      for (int kk = 0; kk < 4; ++kk) { hr[kk] = a[kk]; hr[4 + kk] = bq[kk]; }
    } else if (w >= 14) {
      // ---- poller wave: sentinel poll (device scope) + publish ----
      const int tp = dir ? (t + 1) : (t - 1);
      const float* hp = hsd + (size_t)tp * HD + 8 * L;
      v4i ia, ib;
      do {
        asm volatile("global_load_dwordx4 %0, %2, off sc0 sc1\n"
                     "global_load_dwordx4 %1, %2, off offset:16 sc0 sc1\n"
                     "s_waitcnt vmcnt(0)"
                     : "=&v"(ia), "=&v"(ib) : "v"(hp) : "memory");
      } while (((ia[0] == -1) | (ia[1] == -1) | (ia[2] == -1) | (ia[3] == -1) |
                (ib[0] == -1) | (ib[1] == -1) | (ib[2] == -1) | (ib[3] == -1)) != 0);
      v4f fa, fb;
      #pragma unroll
      for (int kk = 0; kk < 4; ++kk) {
        fa[kk] = __int_as_float(ia[kk]);
        fb[kk] = __int_as_float(ib[kk]);
        hr[kk] = fa[kk]; hr[4 + kk] = fb[kk];
      }
      *(v4f*)&hl[sl][8 * L]     = fa;
      *(v4f*)&hl[sl][8 * L + 4] = fb;
      asm volatile("s_waitcnt lgkmcnt(0)" ::: "memory");
      if (L == 0) atomicAdd((int*)&hrdy[sl], 1);
    } else {
      // ---- compute wave: wait for publication via LDS flag ----
      while (hrdy[sl] < 2) { }
      asm volatile("s_waitcnt lgkmcnt(0)" ::: "memory");
      __builtin_amdgcn_sched_barrier(0);
      v4f a = *(const v4f*)&hl[sl][8 * L];
      v4f bq = *(const v4f*)&hl[sl][8 * L + 4];
      #pragma unroll
      for (int kk = 0; kk < 4; ++kk) { hr[kk] = a[kk]; hr[4 + kk] = bq[kk]; }
    }

    // ---- in-wave dots: 4 gate rows of unit w (bit-exact order) ----
    float tot[4];
    #pragma unroll
    for (int g = 0; g < 4; ++g) {
      float a = 0.f;
      #pragma unroll
      for (int kk = 0; kk < 8; ++kk) a = fmaf(wreg[g][kk], hr[kk], a);
      const float rs = row16_sum(a);
      const float s0 = __shfl(rs, 15);
      const float s1 = __shfl(rs, 31);
      const float s2 = __shfl(rs, 47);
      const float s3 = __shfl(rs, 63);
      tot[g] = ((s0 + s1) + s2) + s3;
    }
    {  // lane g<4 writes gt[sl][g][w] (static-index select, rule #20)
      const float lo = (L & 2) ? tot[2] : tot[0];
      const float hi = (L & 2) ? tot[3] : tot[1];
      const float myv = (L & 1) ? hi : lo;
      if (L < 4) gt[sl][L][w] = myv;
    }
    __syncthreads();  // the ONE barrier: gt complete, hl consumed
    if (tid == 0) hrdy[sl] = 0;  // safe: next increment to this slot is >= 2 steps away

    // ---- redundant tail on every wave ----
    {
      const int g = L >> 4, u = L & 15;
      const float sum = gt[sl][g][u] + xpc;
      const float gv = (g == 2) ? tanhf(sum) : sigmoidf_(sum);
      const float ig = __shfl(gv, u);
      const float fg = __shfl(gv, u + 16);
      const float gg = __shfl(gv, u + 32);
      const float og = __shfl(gv, u + 48);
      if (L < 16) {
        cst = fg * cst + ig * gg;
        const float hval = og * tanhf(cst);
        if (w == 0) {
          float* hp = hsd + (size_t)t * HD + bb * 16 + L;
          asm volatile("global_store_dword %0, %1, off sc0 sc1" :: "v"(hp), "v"(hval) : "memory");
        }
      }
    }
    // prefetch xp for next t (hidden under next step's poll/spin)
    if (s + 1 < T_LEN) {
      const int tn = dir ? (t - 1) : (t + 1);
      xpc = xpd[(size_t)tn * G4 + xcol];
    }
  }
}

// =========================================================
// feats[t][k] = [hs_f[t], hs_b[t]] . w_out[k] + b_out[k]
// =========================================================
__global__ __launch_bounds__(256) void feats_kernel(
    const float* __restrict__ hs, const float* __restrict__ wout,
    const float* __restrict__ bout, float* __restrict__ feats)
{
  __shared__ __align__(16) float xs[32][132];
  __shared__ __align__(16) float wl[34][132];
  const int tid = threadIdx.x;
  const int t0 = blockIdx.x * 32;
  const int m = tid & 31, ng = tid >> 5;
  float acc[5] = {0.f, 0.f, 0.f, 0.f, 0.f};
  for (int cc = 0; cc < 8; ++cc) {
    const int d = cc >> 2;
    const int c0 = (cc & 3) * 128;
    const float* hsrc = hs + (size_t)d * T_LEN * HD;
    const int wcol = d * HD + c0;
    __syncthreads();
    {
      const int row = tid >> 3, seg = tid & 7;
      const float* src = hsrc + (size_t)(t0 + row) * HD + c0 + seg * 16;
      #pragma unroll
      for (int i = 0; i < 4; ++i) {
        v4f v = *(const v4f*)(src + i * 4);
        *(v4f*)&xs[row][seg * 16 + i * 4] = v;
      }
    }
    for (int i = tid; i < 34 * 32; i += 256) {
      const int r = i >> 5, q = i & 31;
      v4f v = *(const v4f*)(wout + (size_t)r * E_DIM + wcol + q * 4);
      *(v4f*)&wl[r][q * 4] = v;
    }
    __syncthreads();
    for (int kq = 0; kq < 32; ++kq) {
      v4f xv = *(const v4f*)&xs[m][kq * 4];
      #pragma unroll
      for (int sl = 0; sl < 5; ++sl) {
        const int n = ng + sl * 8;
        if (n < K_TAGS) {
          v4f wv = *(const v4f*)&wl[n][kq * 4];
          acc[sl] = fmaf(xv[0], wv[0], acc[sl]);
          acc[sl] = fmaf(xv[1], wv[1], acc[sl]);
          acc[sl] = fmaf(xv[2], wv[2], acc[sl]);
          acc[sl] = fmaf(xv[3], wv[3], acc[sl]);
        }
      }
    }
  }
  #pragma unroll
  for (int sl = 0; sl < 5; ++sl) {
    const int n = ng + sl * 8;
    if (n < K_TAGS) feats[(size_t)(t0 + m) * K_TAGS + n] = acc[sl] + bout[n];
  }
}

// =========================================================
// Sequential Viterbi — single wave, no barriers, ordered tree-max
// (first-max tie-break preserved vs np.argmax).
// =========================================================
__global__ __launch_bounds__(64) void viterbi_kernel(
    const float* __restrict__ feats, const float* __restrict__ trans,
    float* __restrict__ d_out, int* __restrict__ bestlast, unsigned char* __restrict__ bp)
{
  const int L = threadIdx.x;
  const int n = (L < K_TAGS) ? L : 0;
  const bool act = (L < K_TAGS);
  float tr[K_TAGS];
  #pragma unroll
  for (int p = 0; p < K_TAGS; ++p) tr[p] = trans[n * K_TAGS + p];
  const float tstop = trans[33 * K_TAGS + n];
  __shared__ float fvs[K_TAGS];
  if (act) fvs[n] = (n == 32) ? 0.f : -10000.f;
  asm volatile("s_waitcnt lgkmcnt(0)" ::: "memory");
  __builtin_amdgcn_sched_barrier(0);

  float feat_next = feats[n];
  float fvreg = 0.f;
  for (int t = 0; t < T_LEN; ++t) {
    const float feat = feat_next;
    if (t + 1 < T_LEN) feat_next = feats[(size_t)(t + 1) * K_TAGS + n];
    float val[K_TAGS];
    int   idx[K_TAGS];
    #pragma unroll
    for (int p = 0; p < K_TAGS; ++p) { val[p] = fvs[p] + tr[p]; idx[p] = p; }
    // ordered tree; right wins only if strictly greater => first-max
    #pragma unroll
    for (int st = 1; st < K_TAGS; st <<= 1) {
      #pragma unroll
      for (int i = 0; i + st < K_TAGS; i += 2 * st) {
        if (val[i + st] > val[i]) { val[i] = val[i + st]; idx[i] = idx[i + st]; }
      }
    }
    fvreg = val[0] + feat;
    if (act) {
      bp[(size_t)t * K_TAGS + n] = (unsigned char)idx[0];
      fvs[n] = fvreg;
    }
    asm volatile("s_waitcnt lgkmcnt(0)" ::: "memory");
    __builtin_amdgcn_sched_barrier(0);
  }
  if (act) fvs[n] = fvreg + tstop;      // terminal scores
  asm volatile("s_waitcnt lgkmcnt(0)" ::: "memory");
  __builtin_amdgcn_sched_barrier(0);
  if (L == 0) {
    float best = -3.4e38f; int bi = 0;
    for (int k = 0; k < K_TAGS; ++k) {
      const float v = fvs[k];
      if (v > best) { best = v; bi = k; }
    }
    d_out[0] = best;
    *bestlast = bi;
  }
}

// =========================================================
// Parallel backtrace: 128 chunks of 64 steps.
// =========================================================
__global__ __launch_bounds__(1024) void backtrace_kernel(
    const unsigned char* __restrict__ bp, const int* __restrict__ bestlast,
    float* __restrict__ d_out)
{
  __shared__ unsigned char exitl[128 * K_TAGS];
  __shared__ unsigned char entl[128];
  const int tid = threadIdx.x;
  for (int W = tid; W < 128 * K_TAGS; W += 1024) {
    const int c = W / K_TAGS;
    int tg = W % K_TAGS;
    for (int t = c * 64 + 63; t >= c * 64; --t) tg = bp[(size_t)t * K_TAGS + tg];
    exitl[W] = (unsigned char)tg;
  }
  __syncthreads();
  if (tid == 0) {
    int tag = *bestlast;
    entl[127] = (unsigned char)tag;
    for (int c = 127; c >= 1; --c) {
      tag = exitl[c * K_TAGS + tag];
      entl[c - 1] = (unsigned char)tag;
    }
  }
  __syncthreads();
  if (tid < 128) {
    const int c = tid;
    int tg = entl[c];
    for (int t = c * 64 + 63; t >= c * 64; --t) {
      d_out[1 + t] = (float)tg;
      tg = bp[(size_t)t * K_TAGS + tg];
    }
  }
}

// =========================================================
extern "C" void kernel_launch(void* const* d_in, const int* in_sizes, int n_in,
                              void* d_out, int out_size, void* d_ws, size_t ws_size,
                              hipStream_t stream)
{
  const float* sent = (const float*)d_in[0];
  const float* h0   = (const float*)d_in[1];
  const float* c0   = (const float*)d_in[2];
  const float* wihf = (const float*)d_in[3];
  const float* whhf = (const float*)d_in[4];
  const float* bihf = (const float*)d_in[5];
  const float* bhhf = (const float*)d_in[6];
  const float* wihb = (const float*)d_in[7];
  const float* whhb = (const float*)d_in[8];
  const float* bihb = (const float*)d_in[9];
  const float* bhhb = (const float*)d_in[10];
  const float* wout = (const float*)d_in[11];
  const float* bout = (const float*)d_in[12];
  const float* trans = (const float*)d_in[13];

  float* out = (float*)d_out;
  char* ws = (char*)d_ws;
  float* xp    = (float*)(ws + XP_OFF);
  float* hs    = (float*)(ws + HS_OFF);
  float* feats = (float*)(ws + FEATS_OFF);
  unsigned char* bp = (unsigned char*)(ws + BP_OFF);
  int* bestlast = (int*)(ws + BEST_OFF);

  // reset hs to the 0xFFFFFFFF sentinel every call (data-driven sync;
  // also makes graph replays deterministic — harness doesn't re-poison)
  hipMemsetAsync(hs, 0xFF, (size_t)2 * T_LEN * HD * sizeof(float), stream);

  // sentence passthrough output
  hipMemcpyAsync(out + 1 + T_LEN, sent, (size_t)T_LEN * E_DIM * sizeof(float),
                 hipMemcpyDeviceToDevice, stream);

  dim3 g1(T_LEN / BM, G4 / BN, 2);
  xp_gemm<<<g1, 256, 0, stream>>>(sent, wihf, wihb, bihf, bhhf, bihb, bhhb, xp);

  lstm_kernel<<<64, 1024, 0, stream>>>(h0, c0, whhf, whhb, xp, hs);

  feats_kernel<<<T_LEN / 32, 256, 0, stream>>>(hs, wout, bout, feats);

  viterbi_kernel<<<1, 64, 0, stream>>>(feats, trans, out, bestlast, bp);

  backtrace_kernel<<<1, 1024, 0, stream>>>(bp, bestlast, out);
}

// Round 9
// 19556.311 us; speedup vs baseline: 1.1376x; 1.1376x over previous
//
#include <hip/hip_runtime.h>
#include <hip/hip_bf16.h>

typedef float v4f __attribute__((ext_vector_type(4)));
typedef int   v4i __attribute__((ext_vector_type(4)));

#define T_LEN 8192
#define E_DIM 1024
#define HD    512
#define G4    2048
#define K_TAGS 34

// ---------------- ws layout (bytes) ----------------
#define XP_OFF      0ull                  // 2 * 8192 * 2048 f32 = 128MB
#define HS_OFF      134217728ull          // 2 * 8192 * 512 f32  = 32MB
#define FEATS_OFF   167772160ull          // 8192*34 f32
#define BP_OFF      168886272ull          // 8192*34 u8
#define BEST_OFF    169165824ull          // int

// =========================================================
// xp GEMM: xp[dir][t][r] = sentence[t] . w_ih[dir][r] + b_ih[r]+b_hh[r]
// (r4 verbatim)
// =========================================================
#define BM 128
#define BN 128
#define BKK 16

__global__ __launch_bounds__(256) void xp_gemm(
    const float* __restrict__ A, const float* __restrict__ Wf, const float* __restrict__ Wb,
    const float* __restrict__ bihf, const float* __restrict__ bhhf,
    const float* __restrict__ bihb, const float* __restrict__ bhhb,
    float* __restrict__ xp)
{
  __shared__ __align__(16) float a_lds[BKK][BM + 4];
  __shared__ __align__(16) float b_lds[BKK][BN + 4];
  const int dir = blockIdx.z;
  const float* W   = dir ? Wb : Wf;
  const float* bih = dir ? bihb : bihf;
  const float* bhh = dir ? bhhb : bhhf;
  const int tid = threadIdx.x;
  const int srow = tid >> 1, sh = (tid & 1) * 8;
  const int tx = tid & 15, ty = tid >> 4;
  const size_t arow = (size_t)(blockIdx.x * BM + srow) * E_DIM;
  const size_t brow = (size_t)(blockIdx.y * BN + srow) * E_DIM;
  float acc[8][8];
  #pragma unroll
  for (int i = 0; i < 8; ++i)
    #pragma unroll
    for (int j = 0; j < 8; ++j) acc[i][j] = 0.f;

  for (int k0 = 0; k0 < E_DIM; k0 += BKK) {
    v4f a0 = *(const v4f*)(A + arow + k0 + sh);
    v4f a1 = *(const v4f*)(A + arow + k0 + sh + 4);
    v4f b0 = *(const v4f*)(W + brow + k0 + sh);
    v4f b1 = *(const v4f*)(W + brow + k0 + sh + 4);
    __syncthreads();
    #pragma unroll
    for (int j = 0; j < 4; ++j) {
      a_lds[sh + j][srow]     = a0[j];
      a_lds[sh + 4 + j][srow] = a1[j];
      b_lds[sh + j][srow]     = b0[j];
      b_lds[sh + 4 + j][srow] = b1[j];
    }
    __syncthreads();
    #pragma unroll
    for (int kk = 0; kk < BKK; ++kk) {
      v4f av0 = *(const v4f*)&a_lds[kk][ty * 8];
      v4f av1 = *(const v4f*)&a_lds[kk][ty * 8 + 4];
      v4f bv0 = *(const v4f*)&b_lds[kk][tx * 4];
      v4f bv1 = *(const v4f*)&b_lds[kk][64 + tx * 4];
      float av[8] = {av0[0],av0[1],av0[2],av0[3],av1[0],av1[1],av1[2],av1[3]};
      float bv[8] = {bv0[0],bv0[1],bv0[2],bv0[3],bv1[0],bv1[1],bv1[2],bv1[3]};
      #pragma unroll
      for (int i = 0; i < 8; ++i)
        #pragma unroll
        for (int j = 0; j < 8; ++j) acc[i][j] = fmaf(av[i], bv[j], acc[i][j]);
    }
  }
  const int gm  = blockIdx.x * BM + ty * 8;
  const int gnl = blockIdx.y * BN + tx * 4;
  const int gnh = gnl + 64;
  float bias[8];
  #pragma unroll
  for (int j = 0; j < 4; ++j) bias[j]     = bih[gnl + j] + bhh[gnl + j];
  #pragma unroll
  for (int j = 0; j < 4; ++j) bias[4 + j] = bih[gnh + j] + bhh[gnh + j];
  float* outp = xp + ((size_t)dir * T_LEN) * G4;
  #pragma unroll
  for (int i = 0; i < 8; ++i) {
    v4f o0 = {acc[i][0]+bias[0], acc[i][1]+bias[1], acc[i][2]+bias[2], acc[i][3]+bias[3]};
    v4f o1 = {acc[i][4]+bias[4], acc[i][5]+bias[5], acc[i][6]+bias[6], acc[i][7]+bias[7]};
    *(v4f*)(outp + (size_t)(gm + i) * G4 + gnl) = o0;
    *(v4f*)(outp + (size_t)(gm + i) * G4 + gnh) = o1;
  }
}

// =========================================================
// Persistent BiLSTM recurrence. 64 blocks (32/dir) x 1024 threads.
// r4 body with one change: wave-role split + phase-aligned poll.
//  - wave0: s_sleep(384cy) then serial sentinel poll (r4 asm verbatim),
//    publish h row to LDS hl. Poll sampling now lands just after the
//    producer store becomes visible -> first-probe hit.
//  - wave1: tail (r4 sum order, r6-proven shfl gather - bit-identical),
//    c-state in lanes<16, coalesced h store (sc0 sc1).
//  - wave2: xp prefetch double-buffer (plain cached loads; xp is fully
//    written before this kernel launches - stream serialized).
//  - all 16 waves: partial dots + red2 (r4 verbatim).
// =========================================================
__device__ __forceinline__ float row16_sum(float x) {
  x += __int_as_float(__builtin_amdgcn_update_dpp(0, __float_as_int(x), 0x111, 0xf, 0xf, true));
  x += __int_as_float(__builtin_amdgcn_update_dpp(0, __float_as_int(x), 0x112, 0xf, 0xf, true));
  x += __int_as_float(__builtin_amdgcn_update_dpp(0, __float_as_int(x), 0x114, 0xf, 0xf, true));
  x += __int_as_float(__builtin_amdgcn_update_dpp(0, __float_as_int(x), 0x118, 0xf, 0xf, true));
  return x; // lane (16q+15) holds sum of its 16-lane group
}

__device__ __forceinline__ float sigmoidf_(float x) { return 1.f / (1.f + expf(-x)); }

__global__ __launch_bounds__(1024) void lstm_kernel(
    const float* __restrict__ h0, const float* __restrict__ c0,
    const float* __restrict__ whhf, const float* __restrict__ whhb,
    const float* __restrict__ xp, float* __restrict__ hs)
{
  const int b = blockIdx.x;
  const int dir = b >> 5, bb = b & 31;
  const int tid = threadIdx.x;
  const int w = tid >> 6, L = tid & 63;
  const float* whh = dir ? whhb : whhf;
  const float* xpd = xp + (size_t)dir * T_LEN * G4;
  float* hsd = hs + (size_t)dir * T_LEN * HD;
  __shared__ __align__(16) float hl[HD];
  __shared__ __align__(16) float red2[16][4][4];
  __shared__ float xpl[2][64];

  // weight preload into VGPRs: wave w owns gate rows 4w..4w+3 (r4 mapping)
  float wreg[4][8];
  #pragma unroll
  for (int j = 0; j < 4; ++j) {
    int r = 4 * w + j;
    int grow = (r >> 4) * HD + bb * 16 + (r & 15);
    const float* p = whh + (size_t)grow * HD + 8 * L;
    v4f q0 = *(const v4f*)p;
    v4f q1 = *(const v4f*)(p + 4);
    #pragma unroll
    for (int kk = 0; kk < 4; ++kk) { wreg[j][kk] = q0[kk]; wreg[j][4 + kk] = q1[kk]; }
  }
  float cst = 0.f;
  if (w == 1 && L < 16) cst = c0[dir * HD + bb * 16 + L];
  // xp prefetch owner: wave2, lane L covers gate row r=L
  const int xcol = (L >> 4) * HD + bb * 16 + (L & 15);
  if (w == 2) xpl[0][L] = xpd[(size_t)(dir ? (T_LEN - 1) : 0) * G4 + xcol];
  __syncthreads();

  for (int s = 0; s < T_LEN; ++s) {
    const int t = dir ? (T_LEN - 1 - s) : s;

    // --- wave0: obtain h_prev (phase-aligned sentinel poll), publish ---
    if (w == 0) {
      if (s == 0) {
        const float* hp = h0 + dir * HD + 8 * L;
        v4f a = *(const v4f*)hp;
        v4f bq = *(const v4f*)(hp + 4);
        *(v4f*)&hl[8 * L]     = a;
        *(v4f*)&hl[8 * L + 4] = bq;
      } else {
        const int tp = dir ? (t + 1) : (t - 1);
        const float* hp = hsd + (size_t)tp * HD + 8 * L;
        // phase alignment: producer (wave1) needs ~350cy tail + store
        // flight; sleep so the first probe SAMPLES just after visibility.
        asm volatile("s_sleep 6" ::: "memory");
        v4i ia, ib;
        do {
          asm volatile("global_load_dwordx4 %0, %2, off sc0 sc1\n"
                       "global_load_dwordx4 %1, %2, off offset:16 sc0 sc1\n"
                       "s_waitcnt vmcnt(0)"
                       : "=&v"(ia), "=&v"(ib) : "v"(hp) : "memory");
        } while (((ia[0] == -1) | (ia[1] == -1) | (ia[2] == -1) | (ia[3] == -1) |
                  (ib[0] == -1) | (ib[1] == -1) | (ib[2] == -1) | (ib[3] == -1)) != 0);
        v4f fa, fb;
        #pragma unroll
        for (int kk = 0; kk < 4; ++kk) { fa[kk] = __int_as_float(ia[kk]); fb[kk] = __int_as_float(ib[kk]); }
        *(v4f*)&hl[8 * L]     = fa;
        *(v4f*)&hl[8 * L + 4] = fb;
      }
    }
    __syncthreads();  // B1: hl visible to all waves

    // --- all 16 waves: partial dots for their 4 gate rows (r4 verbatim) ---
    v4f h0v = *(const v4f*)&hl[8 * L];
    v4f h1v = *(const v4f*)&hl[8 * L + 4];
    float hr[8] = {h0v[0], h0v[1], h0v[2], h0v[3], h1v[0], h1v[1], h1v[2], h1v[3]};
    float a4[4];
    #pragma unroll
    for (int j = 0; j < 4; ++j) {
      float a = 0.f;
      #pragma unroll
      for (int kk = 0; kk < 8; ++kk) a = fmaf(wreg[j][kk], hr[kk], a);
      a4[j] = row16_sum(a);
    }
    if ((L & 15) == 15) {
      int q = L >> 4;
      v4f rv = {a4[0], a4[1], a4[2], a4[3]};
      *(v4f*)&red2[w][q][0] = rv;
    }
    __syncthreads();  // B2: red2 complete

    if (w == 1) {
      // tail on wave1: gate row r=L; sum order bit-identical to r4
      const int u = L & 15;
      const int ww = L >> 2, j = L & 3;
      const float sum = red2[ww][0][j] + red2[ww][1][j] + red2[ww][2][j] + red2[ww][3][j]
                      + xpl[s & 1][L];
      const float gv = ((L >> 4) == 2) ? tanhf(sum) : sigmoidf_(sum);
      const float ig = __shfl(gv, u);
      const float fg = __shfl(gv, u + 16);
      const float gg = __shfl(gv, u + 32);
      const float og = __shfl(gv, u + 48);
      if (L < 16) {
        cst = fg * cst + ig * gg;
        const float hval = og * tanhf(cst);
        float* hp = hsd + (size_t)t * HD + bb * 16 + L;
        asm volatile("global_store_dword %0, %1, off sc0 sc1" :: "v"(hp), "v"(hval) : "memory");
      }
    } else if (w == 2 && s + 1 < T_LEN) {
      const int tn = dir ? (t - 1) : (t + 1);
      xpl[(s + 1) & 1][L] = xpd[(size_t)tn * G4 + xcol];
    }
  }
}

// =========================================================
// feats[t][k] = [hs_f[t], hs_b[t]] . w_out[k] + b_out[k]   (r4 verbatim)
// =========================================================
__global__ __launch_bounds__(256) void feats_kernel(
    const float* __restrict__ hs, const float* __restrict__ wout,
    const float* __restrict__ bout, float* __restrict__ feats)
{
  __shared__ __align__(16) float xs[32][132];
  __shared__ __align__(16) float wl[34][132];
  const int tid = threadIdx.x;
  const int t0 = blockIdx.x * 32;
  const int m = tid & 31, ng = tid >> 5;
  float acc[5] = {0.f, 0.f, 0.f, 0.f, 0.f};
  for (int cc = 0; cc < 8; ++cc) {
    const int d = cc >> 2;
    const int c0 = (cc & 3) * 128;
    const float* hsrc = hs + (size_t)d * T_LEN * HD;
    const int wcol = d * HD + c0;
    __syncthreads();
    {
      const int row = tid >> 3, seg = tid & 7;
      const float* src = hsrc + (size_t)(t0 + row) * HD + c0 + seg * 16;
      #pragma unroll
      for (int i = 0; i < 4; ++i) {
        v4f v = *(const v4f*)(src + i * 4);
        *(v4f*)&xs[row][seg * 16 + i * 4] = v;
      }
    }
    for (int i = tid; i < 34 * 32; i += 256) {
      const int r = i >> 5, q = i & 31;
      v4f v = *(const v4f*)(wout + (size_t)r * E_DIM + wcol + q * 4);
      *(v4f*)&wl[r][q * 4] = v;
    }
    __syncthreads();
    for (int kq = 0; kq < 32; ++kq) {
      v4f xv = *(const v4f*)&xs[m][kq * 4];
      #pragma unroll
      for (int sl = 0; sl < 5; ++sl) {
        const int n = ng + sl * 8;
        if (n < K_TAGS) {
          v4f wv = *(const v4f*)&wl[n][kq * 4];
          acc[sl] = fmaf(xv[0], wv[0], acc[sl]);
          acc[sl] = fmaf(xv[1], wv[1], acc[sl]);
          acc[sl] = fmaf(xv[2], wv[2], acc[sl]);
          acc[sl] = fmaf(xv[3], wv[3], acc[sl]);
        }
      }
    }
  }
  #pragma unroll
  for (int sl = 0; sl < 5; ++sl) {
    const int n = ng + sl * 8;
    if (n < K_TAGS) feats[(size_t)(t0 + m) * K_TAGS + n] = acc[sl] + bout[n];
  }
}

// =========================================================
// Sequential Viterbi — single wave, ordered tree-max (r4 verbatim).
// =========================================================
__global__ __launch_bounds__(64) void viterbi_kernel(
    const float* __restrict__ feats, const float* __restrict__ trans,
    float* __restrict__ d_out, int* __restrict__ bestlast, unsigned char* __restrict__ bp)
{
  const int L = threadIdx.x;
  const int n = (L < K_TAGS) ? L : 0;
  const bool act = (L < K_TAGS);
  float tr[K_TAGS];
  #pragma unroll
  for (int p = 0; p < K_TAGS; ++p) tr[p] = trans[n * K_TAGS + p];
  const float tstop = trans[33 * K_TAGS + n];
  __shared__ float fvs[K_TAGS];
  if (act) fvs[n] = (n == 32) ? 0.f : -10000.f;
  asm volatile("s_waitcnt lgkmcnt(0)" ::: "memory");
  __builtin_amdgcn_sched_barrier(0);

  float feat_next = feats[n];
  float fvreg = 0.f;
  for (int t = 0; t < T_LEN; ++t) {
    const float feat = feat_next;
    if (t + 1 < T_LEN) feat_next = feats[(size_t)(t + 1) * K_TAGS + n];
    float val[K_TAGS];
    int   idx[K_TAGS];
    #pragma unroll
    for (int p = 0; p < K_TAGS; ++p) { val[p] = fvs[p] + tr[p]; idx[p] = p; }
    // ordered tree; right wins only if strictly greater => first-max
    #pragma unroll
    for (int st = 1; st < K_TAGS; st <<= 1) {
      #pragma unroll
      for (int i = 0; i + st < K_TAGS; i += 2 * st) {
        if (val[i + st] > val[i]) { val[i] = val[i + st]; idx[i] = idx[i + st]; }
      }
    }
    fvreg = val[0] + feat;
    if (act) {
      bp[(size_t)t * K_TAGS + n] = (unsigned char)idx[0];
      fvs[n] = fvreg;
    }
    asm volatile("s_waitcnt lgkmcnt(0)" ::: "memory");
    __builtin_amdgcn_sched_barrier(0);
  }
  if (act) fvs[n] = fvreg + tstop;      // terminal scores
  asm volatile("s_waitcnt lgkmcnt(0)" ::: "memory");
  __builtin_amdgcn_sched_barrier(0);
  if (L == 0) {
    float best = -3.4e38f; int bi = 0;
    for (int k = 0; k < K_TAGS; ++k) {
      const float v = fvs[k];
      if (v > best) { best = v; bi = k; }
    }
    d_out[0] = best;
    *bestlast = bi;
  }
}

// =========================================================
// Parallel backtrace: 128 chunks of 64 steps (r4 verbatim).
// =========================================================
__global__ __launch_bounds__(1024) void backtrace_kernel(
    const unsigned char* __restrict__ bp, const int* __restrict__ bestlast,
    float* __restrict__ d_out)
{
  __shared__ unsigned char exitl[128 * K_TAGS];
  __shared__ unsigned char entl[128];
  const int tid = threadIdx.x;
  for (int W = tid; W < 128 * K_TAGS; W += 1024) {
    const int c = W / K_TAGS;
    int tg = W % K_TAGS;
    for (int t = c * 64 + 63; t >= c * 64; --t) tg = bp[(size_t)t * K_TAGS + tg];
    exitl[W] = (unsigned char)tg;
  }
  __syncthreads();
  if (tid == 0) {
    int tag = *bestlast;
    entl[127] = (unsigned char)tag;
    for (int c = 127; c >= 1; --c) {
      tag = exitl[c * K_TAGS + tag];
      entl[c - 1] = (unsigned char)tag;
    }
  }
  __syncthreads();
  if (tid < 128) {
    const int c = tid;
    int tg = entl[c];
    for (int t = c * 64 + 63; t >= c * 64; --t) {
      d_out[1 + t] = (float)tg;
      tg = bp[(size_t)t * K_TAGS + tg];
    }
  }
}

// =========================================================
extern "C" void kernel_launch(void* const* d_in, const int* in_sizes, int n_in,
                              void* d_out, int out_size, void* d_ws, size_t ws_size,
                              hipStream_t stream)
{
  const float* sent = (const float*)d_in[0];
  const float* h0   = (const float*)d_in[1];
  const float* c0   = (const float*)d_in[2];
  const float* wihf = (const float*)d_in[3];
  const float* whhf = (const float*)d_in[4];
  const float* bihf = (const float*)d_in[5];
  const float* bhhf = (const float*)d_in[6];
  const float* wihb = (const float*)d_in[7];
  const float* whhb = (const float*)d_in[8];
  const float* bihb = (const float*)d_in[9];
  const float* bhhb = (const float*)d_in[10];
  const float* wout = (const float*)d_in[11];
  const float* bout = (const float*)d_in[12];
  const float* trans = (const float*)d_in[13];

  float* out = (float*)d_out;
  char* ws = (char*)d_ws;
  float* xp    = (float*)(ws + XP_OFF);
  float* hs    = (float*)(ws + HS_OFF);
  float* feats = (float*)(ws + FEATS_OFF);
  unsigned char* bp = (unsigned char*)(ws + BP_OFF);
  int* bestlast = (int*)(ws + BEST_OFF);

  // reset hs to the 0xFFFFFFFF sentinel every call (data-driven sync;
  // also makes graph replays deterministic — harness doesn't re-poison)
  hipMemsetAsync(hs, 0xFF, (size_t)2 * T_LEN * HD * sizeof(float), stream);

  // sentence passthrough output
  hipMemcpyAsync(out + 1 + T_LEN, sent, (size_t)T_LEN * E_DIM * sizeof(float),
                 hipMemcpyDeviceToDevice, stream);

  dim3 g1(T_LEN / BM, G4 / BN, 2);
  xp_gemm<<<g1, 256, 0, stream>>>(sent, wihf, wihb, bihf, bhhf, bihb, bhhb, xp);

  lstm_kernel<<<64, 1024, 0, stream>>>(h0, c0, whhf, whhb, xp, hs);

  feats_kernel<<<T_LEN / 32, 256, 0, stream>>>(hs, wout, bout, feats);

  viterbi_kernel<<<1, 64, 0, stream>>>(feats, trans, out, bestlast, bp);

  backtrace_kernel<<<1, 1024, 0, stream>>>(bp, bestlast, out);
}

// Round 10
// 19143.570 us; speedup vs baseline: 1.1622x; 1.0216x over previous
//
#include <hip/hip_runtime.h>
#include <hip/hip_bf16.h>

typedef float v4f __attribute__((ext_vector_type(4)));
typedef int   v4i __attribute__((ext_vector_type(4)));

#define T_LEN 8192
#define E_DIM 1024
#define HD    512
#define G4    2048
#define K_TAGS 34

// ---------------- ws layout (bytes) ----------------
#define XP_OFF      0ull                  // 2 * 8192 * 2048 f32 = 128MB
#define HS_OFF      134217728ull          // 2 * 8192 * 512 f32  = 32MB
#define FEATS_OFF   167772160ull          // 8192*34 f32
#define BP_OFF      168886272ull          // 8192*34 u8
#define BEST_OFF    169165824ull          // int

#define SENT32 0xFFFFFFFFu

// sentinel-poll load: cached fast path (stale line can only show the
// sentinel or the bit-identical prior-replay value) + coherent retry.
__device__ __forceinline__ float xp_sent_ld(const float* p) {
  unsigned u = *(const unsigned*)p;
  while (u == SENT32) {
    asm volatile("global_load_dword %0, %1, off sc0 sc1\ns_waitcnt vmcnt(0)"
                 : "=v"(u) : "v"(p) : "memory");
  }
  return __uint_as_float(u);
}

__device__ __forceinline__ float row16_sum(float x) {
  x += __int_as_float(__builtin_amdgcn_update_dpp(0, __float_as_int(x), 0x111, 0xf, 0xf, true));
  x += __int_as_float(__builtin_amdgcn_update_dpp(0, __float_as_int(x), 0x112, 0xf, 0xf, true));
  x += __int_as_float(__builtin_amdgcn_update_dpp(0, __float_as_int(x), 0x114, 0xf, 0xf, true));
  x += __int_as_float(__builtin_amdgcn_update_dpp(0, __float_as_int(x), 0x118, 0xf, 0xf, true));
  return x; // lane (16q+15) holds sum of its 16-lane group
}

__device__ __forceinline__ float sigmoidf_(float x) { return 1.f / (1.f + expf(-x)); }

#define BM 128
#define BN 128
#define BKK 16

// =========================================================
// gemm role (blocks 64..575): four r9-verbatim 256-thread tiles packed
// as quarter-blocks (tid&255). Stores with coherent sc0 sc1 asm so lstm
// blocks (same dispatch) see them. Never waits on anything.
// =========================================================
__device__ void gemm_role(int g, const float* A, const float* Wf, const float* Wb,
    const float* bihf, const float* bhhf,
    const float* bihb, const float* bhhb, float* xp)
{
  const int dir  = g & 1;
  const int u    = g >> 1;
  const int rank = u >> 2, nq = u & 3;
  const int bx = dir ? (63 - rank) : rank;        // t-tile (urgency order)
  const int quarter = threadIdx.x >> 8;
  const int by = nq * 4 + quarter;                // n-tile
  const int tid = threadIdx.x & 255;

  __shared__ __align__(16) float a_lds[4][BKK][BM + 4];
  __shared__ __align__(16) float b_lds[4][BKK][BN + 4];

  const float* W   = dir ? Wb : Wf;
  const float* bih = dir ? bihb : bihf;
  const float* bhh = dir ? bhhb : bhhf;
  const int srow = tid >> 1, sh = (tid & 1) * 8;
  const int tx = tid & 15, ty = tid >> 4;
  const size_t arow = (size_t)(bx * BM + srow) * E_DIM;
  const size_t brow = (size_t)(by * BN + srow) * E_DIM;
  float acc[8][8];
  #pragma unroll
  for (int i = 0; i < 8; ++i)
    #pragma unroll
    for (int j = 0; j < 8; ++j) acc[i][j] = 0.f;

  for (int k0 = 0; k0 < E_DIM; k0 += BKK) {
    v4f a0 = *(const v4f*)(A + arow + k0 + sh);
    v4f a1 = *(const v4f*)(A + arow + k0 + sh + 4);
    v4f b0 = *(const v4f*)(W + brow + k0 + sh);
    v4f b1 = *(const v4f*)(W + brow + k0 + sh + 4);
    __syncthreads();
    #pragma unroll
    for (int j = 0; j < 4; ++j) {
      a_lds[quarter][sh + j][srow]     = a0[j];
      a_lds[quarter][sh + 4 + j][srow] = a1[j];
      b_lds[quarter][sh + j][srow]     = b0[j];
      b_lds[quarter][sh + 4 + j][srow] = b1[j];
    }
    __syncthreads();
    #pragma unroll
    for (int kk = 0; kk < BKK; ++kk) {
      v4f av0 = *(const v4f*)&a_lds[quarter][kk][ty * 8];
      v4f av1 = *(const v4f*)&a_lds[quarter][kk][ty * 8 + 4];
      v4f bv0 = *(const v4f*)&b_lds[quarter][kk][tx * 4];
      v4f bv1 = *(const v4f*)&b_lds[quarter][kk][64 + tx * 4];
      float av[8] = {av0[0],av0[1],av0[2],av0[3],av1[0],av1[1],av1[2],av1[3]};
      float bv[8] = {bv0[0],bv0[1],bv0[2],bv0[3],bv1[0],bv1[1],bv1[2],bv1[3]};
      #pragma unroll
      for (int i = 0; i < 8; ++i)
        #pragma unroll
        for (int j = 0; j < 8; ++j) acc[i][j] = fmaf(av[i], bv[j], acc[i][j]);
    }
  }
  const int gm  = bx * BM + ty * 8;
  const int gnl = by * BN + tx * 4;
  const int gnh = gnl + 64;
  float bias[8];
  #pragma unroll
  for (int j = 0; j < 4; ++j) bias[j]     = bih[gnl + j] + bhh[gnl + j];
  #pragma unroll
  for (int j = 0; j < 4; ++j) bias[4 + j] = bih[gnh + j] + bhh[gnh + j];
  float* outp = xp + ((size_t)dir * T_LEN) * G4;
  #pragma unroll
  for (int i = 0; i < 8; ++i) {
    v4f o0 = {acc[i][0]+bias[0], acc[i][1]+bias[1], acc[i][2]+bias[2], acc[i][3]+bias[3]};
    v4f o1 = {acc[i][4]+bias[4], acc[i][5]+bias[5], acc[i][6]+bias[6], acc[i][7]+bias[7]};
    float* p0 = outp + (size_t)(gm + i) * G4 + gnl;
    float* p1 = outp + (size_t)(gm + i) * G4 + gnh;
    asm volatile("global_store_dwordx4 %0, %1, off sc0 sc1" :: "v"(p0), "v"(o0) : "memory");
    asm volatile("global_store_dwordx4 %0, %1, off sc0 sc1" :: "v"(p1), "v"(o1) : "memory");
  }
}

// =========================================================
// lstm role (blocks 0..63): r9 verbatim except wave2's xp loads are
// sentinel-polled (xp now produced concurrently by gemm blocks).
// =========================================================
__device__ void lstm_role(int b, const float* h0, const float* c0,
    const float* whhf, const float* whhb, const float* xp, float* hs)
{
  const int dir = b >> 5, bb = b & 31;
  const int tid = threadIdx.x;
  const int w = tid >> 6, L = tid & 63;
  const float* whh = dir ? whhb : whhf;
  const float* xpd = xp + (size_t)dir * T_LEN * G4;
  float* hsd = hs + (size_t)dir * T_LEN * HD;
  __shared__ __align__(16) float hl[HD];
  __shared__ __align__(16) float red2[16][4][4];
  __shared__ float xpl[2][64];

  // weight preload into VGPRs: wave w owns gate rows 4w..4w+3
  float wreg[4][8];
  #pragma unroll
  for (int j = 0; j < 4; ++j) {
    int r = 4 * w + j;
    int grow = (r >> 4) * HD + bb * 16 + (r & 15);
    const float* p = whh + (size_t)grow * HD + 8 * L;
    v4f q0 = *(const v4f*)p;
    v4f q1 = *(const v4f*)(p + 4);
    #pragma unroll
    for (int kk = 0; kk < 4; ++kk) { wreg[j][kk] = q0[kk]; wreg[j][4 + kk] = q1[kk]; }
  }
  float cst = 0.f;
  if (w == 1 && L < 16) cst = c0[dir * HD + bb * 16 + L];
  const int xcol = (L >> 4) * HD + bb * 16 + (L & 15);
  if (w == 2) xpl[0][L] = xp_sent_ld(xpd + (size_t)(dir ? (T_LEN - 1) : 0) * G4 + xcol);
  __syncthreads();

  for (int s = 0; s < T_LEN; ++s) {
    const int t = dir ? (T_LEN - 1 - s) : s;

    // --- wave0: obtain h_prev (phase-aligned sentinel poll), publish ---
    if (w == 0) {
      if (s == 0) {
        const float* hp = h0 + dir * HD + 8 * L;
        v4f a = *(const v4f*)hp;
        v4f bq = *(const v4f*)(hp + 4);
        *(v4f*)&hl[8 * L]     = a;
        *(v4f*)&hl[8 * L + 4] = bq;
      } else {
        const int tp = dir ? (t + 1) : (t - 1);
        const float* hp = hsd + (size_t)tp * HD + 8 * L;
        asm volatile("s_sleep 6" ::: "memory");
        v4i ia, ib;
        do {
          asm volatile("global_load_dwordx4 %0, %2, off sc0 sc1\n"
                       "global_load_dwordx4 %1, %2, off offset:16 sc0 sc1\n"
                       "s_waitcnt vmcnt(0)"
                       : "=&v"(ia), "=&v"(ib) : "v"(hp) : "memory");
        } while (((ia[0] == -1) | (ia[1] == -1) | (ia[2] == -1) | (ia[3] == -1) |
                  (ib[0] == -1) | (ib[1] == -1) | (ib[2] == -1) | (ib[3] == -1)) != 0);
        v4f fa, fb;
        #pragma unroll
        for (int kk = 0; kk < 4; ++kk) { fa[kk] = __int_as_float(ia[kk]); fb[kk] = __int_as_float(ib[kk]); }
        *(v4f*)&hl[8 * L]     = fa;
        *(v4f*)&hl[8 * L + 4] = fb;
      }
    }
    __syncthreads();  // B1: hl visible to all waves

    // --- all 16 waves: partial dots for their 4 gate rows ---
    v4f h0v = *(const v4f*)&hl[8 * L];
    v4f h1v = *(const v4f*)&hl[8 * L + 4];
    float hr[8] = {h0v[0], h0v[1], h0v[2], h0v[3], h1v[0], h1v[1], h1v[2], h1v[3]};
    float a4[4];
    #pragma unroll
    for (int j = 0; j < 4; ++j) {
      float a = 0.f;
      #pragma unroll
      for (int kk = 0; kk < 8; ++kk) a = fmaf(wreg[j][kk], hr[kk], a);
      a4[j] = row16_sum(a);
    }
    if ((L & 15) == 15) {
      int q = L >> 4;
      v4f rv = {a4[0], a4[1], a4[2], a4[3]};
      *(v4f*)&red2[w][q][0] = rv;
    }
    __syncthreads();  // B2: red2 complete

    if (w == 1) {
      // tail on wave1: gate row r=L; sum order bit-identical to r4/r9
      const int u = L & 15;
      const int ww = L >> 2, j = L & 3;
      const float sum = red2[ww][0][j] + red2[ww][1][j] + red2[ww][2][j] + red2[ww][3][j]
                      + xpl[s & 1][L];
      const float gv = ((L >> 4) == 2) ? tanhf(sum) : sigmoidf_(sum);
      const float ig = __shfl(gv, u);
      const float fg = __shfl(gv, u + 16);
      const float gg = __shfl(gv, u + 32);
      const float og = __shfl(gv, u + 48);
      if (L < 16) {
        cst = fg * cst + ig * gg;
        const float hval = og * tanhf(cst);
        float* hp = hsd + (size_t)t * HD + bb * 16 + L;
        asm volatile("global_store_dword %0, %1, off sc0 sc1" :: "v"(hp), "v"(hval) : "memory");
      }
    } else if (w == 2 && s + 1 < T_LEN) {
      const int tn = dir ? (t - 1) : (t + 1);
      xpl[(s + 1) & 1][L] = xp_sent_ld(xpd + (size_t)tn * G4 + xcol);
    }
  }
}

// =========================================================
// fused gemm+lstm kernel. Blocks 0..63 lstm, 64..575 gemm.
// gemm blocks never wait => always drain => no deadlock possible.
// =========================================================
__global__ __launch_bounds__(1024) void gemm_lstm_kernel(
    const float* __restrict__ sent, const float* __restrict__ h0,
    const float* __restrict__ c0,
    const float* __restrict__ wihf, const float* __restrict__ whhf,
    const float* __restrict__ bihf, const float* __restrict__ bhhf,
    const float* __restrict__ wihb, const float* __restrict__ whhb,
    const float* __restrict__ bihb, const float* __restrict__ bhhb,
    float* __restrict__ xp, float* __restrict__ hs)
{
  const int b = blockIdx.x;
  if (b < 64) lstm_role(b, h0, c0, whhf, whhb, xp, hs);
  else        gemm_role(b - 64, sent, wihf, wihb, bihf, bhhf, bihb, bhhb, xp);
}

// =========================================================
// feats[t][k] = [hs_f[t], hs_b[t]] . w_out[k] + b_out[k]   (r9 verbatim)
// =========================================================
__global__ __launch_bounds__(256) void feats_kernel(
    const float* __restrict__ hs, const float* __restrict__ wout,
    const float* __restrict__ bout, float* __restrict__ feats)
{
  __shared__ __align__(16) float xs[32][132];
  __shared__ __align__(16) float wl[34][132];
  const int tid = threadIdx.x;
  const int t0 = blockIdx.x * 32;
  const int m = tid & 31, ng = tid >> 5;
  float acc[5] = {0.f, 0.f, 0.f, 0.f, 0.f};
  for (int cc = 0; cc < 8; ++cc) {
    const int d = cc >> 2;
    const int c0 = (cc & 3) * 128;
    const float* hsrc = hs + (size_t)d * T_LEN * HD;
    const int wcol = d * HD + c0;
    __syncthreads();
    {
      const int row = tid >> 3, seg = tid & 7;
      const float* src = hsrc + (size_t)(t0 + row) * HD + c0 + seg * 16;
      #pragma unroll
      for (int i = 0; i < 4; ++i) {
        v4f v = *(const v4f*)(src + i * 4);
        *(v4f*)&xs[row][seg * 16 + i * 4] = v;
      }
    }
    for (int i = tid; i < 34 * 32; i += 256) {
      const int r = i >> 5, q = i & 31;
      v4f v = *(const v4f*)(wout + (size_t)r * E_DIM + wcol + q * 4);
      *(v4f*)&wl[r][q * 4] = v;
    }
    __syncthreads();
    for (int kq = 0; kq < 32; ++kq) {
      v4f xv = *(const v4f*)&xs[m][kq * 4];
      #pragma unroll
      for (int sl = 0; sl < 5; ++sl) {
        const int n = ng + sl * 8;
        if (n < K_TAGS) {
          v4f wv = *(const v4f*)&wl[n][kq * 4];
          acc[sl] = fmaf(xv[0], wv[0], acc[sl]);
          acc[sl] = fmaf(xv[1], wv[1], acc[sl]);
          acc[sl] = fmaf(xv[2], wv[2], acc[sl]);
          acc[sl] = fmaf(xv[3], wv[3], acc[sl]);
        }
      }
    }
  }
  #pragma unroll
  for (int sl = 0; sl < 5; ++sl) {
    const int n = ng + sl * 8;
    if (n < K_TAGS) feats[(size_t)(t0 + m) * K_TAGS + n] = acc[sl] + bout[n];
  }
}

// =========================================================
// Sequential Viterbi — single wave, ordered tree-max (r9 verbatim).
// =========================================================
__global__ __launch_bounds__(64) void viterbi_kernel(
    const float* __restrict__ feats, const float* __restrict__ trans,
    float* __restrict__ d_out, int* __restrict__ bestlast, unsigned char* __restrict__ bp)
{
  const int L = threadIdx.x;
  const int n = (L < K_TAGS) ? L : 0;
  const bool act = (L < K_TAGS);
  float tr[K_TAGS];
  #pragma unroll
  for (int p = 0; p < K_TAGS; ++p) tr[p] = trans[n * K_TAGS + p];
  const float tstop = trans[33 * K_TAGS + n];
  __shared__ float fvs[K_TAGS];
  if (act) fvs[n] = (n == 32) ? 0.f : -10000.f;
  asm volatile("s_waitcnt lgkmcnt(0)" ::: "memory");
  __builtin_amdgcn_sched_barrier(0);

  float feat_next = feats[n];
  float fvreg = 0.f;
  for (int t = 0; t < T_LEN; ++t) {
    const float feat = feat_next;
    if (t + 1 < T_LEN) feat_next = feats[(size_t)(t + 1) * K_TAGS + n];
    float val[K_TAGS];
    int   idx[K_TAGS];
    #pragma unroll
    for (int p = 0; p < K_TAGS; ++p) { val[p] = fvs[p] + tr[p]; idx[p] = p; }
    // ordered tree; right wins only if strictly greater => first-max
    #pragma unroll
    for (int st = 1; st < K_TAGS; st <<= 1) {
      #pragma unroll
      for (int i = 0; i + st < K_TAGS; i += 2 * st) {
        if (val[i + st] > val[i]) { val[i] = val[i + st]; idx[i] = idx[i + st]; }
      }
    }
    fvreg = val[0] + feat;
    if (act) {
      bp[(size_t)t * K_TAGS + n] = (unsigned char)idx[0];
      fvs[n] = fvreg;
    }
    asm volatile("s_waitcnt lgkmcnt(0)" ::: "memory");
    __builtin_amdgcn_sched_barrier(0);
  }
  if (act) fvs[n] = fvreg + tstop;      // terminal scores
  asm volatile("s_waitcnt lgkmcnt(0)" ::: "memory");
  __builtin_amdgcn_sched_barrier(0);
  if (L == 0) {
    float best = -3.4e38f; int bi = 0;
    for (int k = 0; k < K_TAGS; ++k) {
      const float v = fvs[k];
      if (v > best) { best = v; bi = k; }
    }
    d_out[0] = best;
    *bestlast = bi;
  }
}

// =========================================================
// Parallel backtrace: 128 chunks of 64 steps (r9 verbatim).
// =========================================================
__global__ __launch_bounds__(1024) void backtrace_kernel(
    const unsigned char* __restrict__ bp, const int* __restrict__ bestlast,
    float* __restrict__ d_out)
{
  __shared__ unsigned char exitl[128 * K_TAGS];
  __shared__ unsigned char entl[128];
  const int tid = threadIdx.x;
  for (int W = tid; W < 128 * K_TAGS; W += 1024) {
    const int c = W / K_TAGS;
    int tg = W % K_TAGS;
    for (int t = c * 64 + 63; t >= c * 64; --t) tg = bp[(size_t)t * K_TAGS + tg];
    exitl[W] = (unsigned char)tg;
  }
  __syncthreads();
  if (tid == 0) {
    int tag = *bestlast;
    entl[127] = (unsigned char)tag;
    for (int c = 127; c >= 1; --c) {
      tag = exitl[c * K_TAGS + tag];
      entl[c - 1] = (unsigned char)tag;
    }
  }
  __syncthreads();
  if (tid < 128) {
    const int c = tid;
    int tg = entl[c];
    for (int t = c * 64 + 63; t >= c * 64; --t) {
      d_out[1 + t] = (float)tg;
      tg = bp[(size_t)t * K_TAGS + tg];
    }
  }
}

// =========================================================
extern "C" void kernel_launch(void* const* d_in, const int* in_sizes, int n_in,
                              void* d_out, int out_size, void* d_ws, size_t ws_size,
                              hipStream_t stream)
{
  const float* sent = (const float*)d_in[0];
  const float* h0   = (const float*)d_in[1];
  const float* c0   = (const float*)d_in[2];
  const float* wihf = (const float*)d_in[3];
  const float* whhf = (const float*)d_in[4];
  const float* bihf = (const float*)d_in[5];
  const float* bhhf = (const float*)d_in[6];
  const float* wihb = (const float*)d_in[7];
  const float* whhb = (const float*)d_in[8];
  const float* bihb = (const float*)d_in[9];
  const float* bhhb = (const float*)d_in[10];
  const float* wout = (const float*)d_in[11];
  const float* bout = (const float*)d_in[12];
  const float* trans = (const float*)d_in[13];

  float* out = (float*)d_out;
  char* ws = (char*)d_ws;
  float* xp    = (float*)(ws + XP_OFF);
  float* hs    = (float*)(ws + HS_OFF);
  float* feats = (float*)(ws + FEATS_OFF);
  unsigned char* bp = (unsigned char*)(ws + BP_OFF);
  int* bestlast = (int*)(ws + BEST_OFF);

  // sentinel both staging buffers every call (data-driven sync;
  // also makes graph replays deterministic — harness doesn't re-poison)
  hipMemsetAsync(xp, 0xFF, (size_t)2 * T_LEN * G4 * sizeof(float), stream);
  hipMemsetAsync(hs, 0xFF, (size_t)2 * T_LEN * HD * sizeof(float), stream);

  // sentence passthrough output
  hipMemcpyAsync(out + 1 + T_LEN, sent, (size_t)T_LEN * E_DIM * sizeof(float),
                 hipMemcpyDeviceToDevice, stream);

  gemm_lstm_kernel<<<576, 1024, 0, stream>>>(
      sent, h0, c0, wihf, whhf, bihf, bhhf, wihb, whhb, bihb, bhhb, xp, hs);

  feats_kernel<<<T_LEN / 32, 256, 0, stream>>>(hs, wout, bout, feats);

  viterbi_kernel<<<1, 64, 0, stream>>>(feats, trans, out, bestlast, bp);

  backtrace_kernel<<<1, 1024, 0, stream>>>(bp, bestlast, out);
}

// Round 12
// 18995.226 us; speedup vs baseline: 1.1712x; 1.0078x over previous
//
#include <hip/hip_runtime.h>
#include <hip/hip_bf16.h>

typedef float v4f __attribute__((ext_vector_type(4)));
typedef int   v4i __attribute__((ext_vector_type(4)));

#define T_LEN 8192
#define E_DIM 1024
#define HD    512
#define G4    2048
#define K_TAGS 34

// ---------------- ws layout (bytes) ----------------
#define XP_OFF      0ull                  // 2 * 8192 * 2048 f32 = 128MB
#define HS_OFF      134217728ull          // 2 * 8192 * 512 f32  = 32MB
#define FEATS_OFF   167772160ull          // 8192*34 f32
#define BP_OFF      168886272ull          // 8192*34 u8
#define CTRL_OFF    169164800ull          // int[16]: [0]=lstm-done count, [1]=vit-done flag
#define BEST_OFF    169165824ull          // int

#define SENT32 0xFFFFFFFFu

__device__ __forceinline__ unsigned coh_ld_u32(const void* p) {
  unsigned r;
  asm volatile("global_load_dword %0, %1, off sc0 sc1\ns_waitcnt vmcnt(0)"
               : "=v"(r) : "v"(p) : "memory");
  __builtin_amdgcn_sched_barrier(0);
  return r;
}

// sentinel-poll load: cached fast path + coherent retry (write-once data).
__device__ __forceinline__ float xp_sent_ld(const float* p) {
  unsigned u = *(const unsigned*)p;
  while (u == SENT32) {
    asm volatile("global_load_dword %0, %1, off sc0 sc1\ns_waitcnt vmcnt(0)"
                 : "=v"(u) : "v"(p) : "memory");
  }
  return __uint_as_float(u);
}

__device__ __forceinline__ float row16_sum(float x) {
  x += __int_as_float(__builtin_amdgcn_update_dpp(0, __float_as_int(x), 0x111, 0xf, 0xf, true));
  x += __int_as_float(__builtin_amdgcn_update_dpp(0, __float_as_int(x), 0x112, 0xf, 0xf, true));
  x += __int_as_float(__builtin_amdgcn_update_dpp(0, __float_as_int(x), 0x114, 0xf, 0xf, true));
  x += __int_as_float(__builtin_amdgcn_update_dpp(0, __float_as_int(x), 0x118, 0xf, 0xf, true));
  return x; // lane (16q+15) holds sum of its 16-lane group
}

__device__ __forceinline__ float sigmoidf_(float x) { return 1.f / (1.f + expf(-x)); }

// keep-clock burn: dense FMA until *flag >= target (coh-polled by tid0)
// or budget expires. Gates nothing; nothing gates on it.
__device__ void spin_burn(const int* flagp, unsigned target, int budget) {
  volatile __shared__ int sflag;
  const int tid = threadIdx.x;
  if (tid == 0) sflag = 0;
  __syncthreads();
  float a0 = 1.f, a1 = 1.f, a2 = 1.f, a3 = 1.f;
  while (--budget >= 0) {
    if (tid == 0 && coh_ld_u32(flagp) >= target) sflag = 1;
    if (sflag) break;
    #pragma unroll
    for (int i = 0; i < 64; ++i) {
      a0 = fmaf(a0, 1.0000001f, 1e-9f);
      a1 = fmaf(a1, 1.0000001f, 1e-9f);
      a2 = fmaf(a2, 1.0000001f, 1e-9f);
      a3 = fmaf(a3, 1.0000001f, 1e-9f);
    }
  }
  asm volatile("" :: "v"(a0), "v"(a1), "v"(a2), "v"(a3));
}

#define BM 128
#define BN 128
#define BKK 16

// =========================================================
// gemm role (blocks 64..575): r10 verbatim.
// =========================================================
__device__ void gemm_role(int g, const float* A, const float* Wf, const float* Wb,
    const float* bihf, const float* bhhf,
    const float* bihb, const float* bhhb, float* xp)
{
  const int dir  = g & 1;
  const int u    = g >> 1;
  const int rank = u >> 2, nq = u & 3;
  const int bx = dir ? (63 - rank) : rank;        // t-tile (urgency order)
  const int quarter = threadIdx.x >> 8;
  const int by = nq * 4 + quarter;                // n-tile
  const int tid = threadIdx.x & 255;

  __shared__ __align__(16) float a_lds[4][BKK][BM + 4];
  __shared__ __align__(16) float b_lds[4][BKK][BN + 4];

  const float* W   = dir ? Wb : Wf;
  const float* bih = dir ? bihb : bihf;
  const float* bhh = dir ? bhhb : bhhf;
  const int srow = tid >> 1, sh = (tid & 1) * 8;
  const int tx = tid & 15, ty = tid >> 4;
  const size_t arow = (size_t)(bx * BM + srow) * E_DIM;
  const size_t brow = (size_t)(by * BN + srow) * E_DIM;
  float acc[8][8];
  #pragma unroll
  for (int i = 0; i < 8; ++i)
    #pragma unroll
    for (int j = 0; j < 8; ++j) acc[i][j] = 0.f;

  for (int k0 = 0; k0 < E_DIM; k0 += BKK) {
    v4f a0 = *(const v4f*)(A + arow + k0 + sh);
    v4f a1 = *(const v4f*)(A + arow + k0 + sh + 4);
    v4f b0 = *(const v4f*)(W + brow + k0 + sh);
    v4f b1 = *(const v4f*)(W + brow + k0 + sh + 4);
    __syncthreads();
    #pragma unroll
    for (int j = 0; j < 4; ++j) {
      a_lds[quarter][sh + j][srow]     = a0[j];
      a_lds[quarter][sh + 4 + j][srow] = a1[j];
      b_lds[quarter][sh + j][srow]     = b0[j];
      b_lds[quarter][sh + 4 + j][srow] = b1[j];
    }
    __syncthreads();
    #pragma unroll
    for (int kk = 0; kk < BKK; ++kk) {
      v4f av0 = *(const v4f*)&a_lds[quarter][kk][ty * 8];
      v4f av1 = *(const v4f*)&a_lds[quarter][kk][ty * 8 + 4];
      v4f bv0 = *(const v4f*)&b_lds[quarter][kk][tx * 4];
      v4f bv1 = *(const v4f*)&b_lds[quarter][kk][64 + tx * 4];
      float av[8] = {av0[0],av0[1],av0[2],av0[3],av1[0],av1[1],av1[2],av1[3]};
      float bv[8] = {bv0[0],bv0[1],bv0[2],bv0[3],bv1[0],bv1[1],bv1[2],bv1[3]};
      #pragma unroll
      for (int i = 0; i < 8; ++i)
        #pragma unroll
        for (int j = 0; j < 8; ++j) acc[i][j] = fmaf(av[i], bv[j], acc[i][j]);
    }
  }
  const int gm  = bx * BM + ty * 8;
  const int gnl = by * BN + tx * 4;
  const int gnh = gnl + 64;
  float bias[8];
  #pragma unroll
  for (int j = 0; j < 4; ++j) bias[j]     = bih[gnl + j] + bhh[gnl + j];
  #pragma unroll
  for (int j = 0; j < 4; ++j) bias[4 + j] = bih[gnh + j] + bhh[gnh + j];
  float* outp = xp + ((size_t)dir * T_LEN) * G4;
  #pragma unroll
  for (int i = 0; i < 8; ++i) {
    v4f o0 = {acc[i][0]+bias[0], acc[i][1]+bias[1], acc[i][2]+bias[2], acc[i][3]+bias[3]};
    v4f o1 = {acc[i][4]+bias[4], acc[i][5]+bias[5], acc[i][6]+bias[6], acc[i][7]+bias[7]};
    float* p0 = outp + (size_t)(gm + i) * G4 + gnl;
    float* p1 = outp + (size_t)(gm + i) * G4 + gnh;
    asm volatile("global_store_dwordx4 %0, %1, off sc0 sc1" :: "v"(p0), "v"(o0) : "memory");
    asm volatile("global_store_dwordx4 %0, %1, off sc0 sc1" :: "v"(p1), "v"(o1) : "memory");
  }
}

// =========================================================
// lstm role (blocks 0..63): r10 verbatim + done-count at the end.
// =========================================================
__device__ void lstm_role(int b, const float* h0, const float* c0,
    const float* whhf, const float* whhb, const float* xp, float* hs,
    int* ctrl)
{
  const int dir = b >> 5, bb = b & 31;
  const int tid = threadIdx.x;
  const int w = tid >> 6, L = tid & 63;
  const float* whh = dir ? whhb : whhf;
  const float* xpd = xp + (size_t)dir * T_LEN * G4;
  float* hsd = hs + (size_t)dir * T_LEN * HD;
  __shared__ __align__(16) float hl[HD];
  __shared__ __align__(16) float red2[16][4][4];
  __shared__ float xpl[2][64];

  // weight preload into VGPRs: wave w owns gate rows 4w..4w+3
  float wreg[4][8];
  #pragma unroll
  for (int j = 0; j < 4; ++j) {
    int r = 4 * w + j;
    int grow = (r >> 4) * HD + bb * 16 + (r & 15);
    const float* p = whh + (size_t)grow * HD + 8 * L;
    v4f q0 = *(const v4f*)p;
    v4f q1 = *(const v4f*)(p + 4);
    #pragma unroll
    for (int kk = 0; kk < 4; ++kk) { wreg[j][kk] = q0[kk]; wreg[j][4 + kk] = q1[kk]; }
  }
  float cst = 0.f;
  if (w == 1 && L < 16) cst = c0[dir * HD + bb * 16 + L];
  const int xcol = (L >> 4) * HD + bb * 16 + (L & 15);
  if (w == 2) xpl[0][L] = xp_sent_ld(xpd + (size_t)(dir ? (T_LEN - 1) : 0) * G4 + xcol);
  __syncthreads();

  for (int s = 0; s < T_LEN; ++s) {
    const int t = dir ? (T_LEN - 1 - s) : s;

    // --- wave0: obtain h_prev (phase-aligned sentinel poll), publish ---
    if (w == 0) {
      if (s == 0) {
        const float* hp = h0 + dir * HD + 8 * L;
        v4f a = *(const v4f*)hp;
        v4f bq = *(const v4f*)(hp + 4);
        *(v4f*)&hl[8 * L]     = a;
        *(v4f*)&hl[8 * L + 4] = bq;
      } else {
        const int tp = dir ? (t + 1) : (t - 1);
        const float* hp = hsd + (size_t)tp * HD + 8 * L;
        asm volatile("s_sleep 6" ::: "memory");
        v4i ia, ib;
        do {
          asm volatile("global_load_dwordx4 %0, %2, off sc0 sc1\n"
                       "global_load_dwordx4 %1, %2, off offset:16 sc0 sc1\n"
                       "s_waitcnt vmcnt(0)"
                       : "=&v"(ia), "=&v"(ib) : "v"(hp) : "memory");
        } while (((ia[0] == -1) | (ia[1] == -1) | (ia[2] == -1) | (ia[3] == -1) |
                  (ib[0] == -1) | (ib[1] == -1) | (ib[2] == -1) | (ib[3] == -1)) != 0);
        v4f fa, fb;
        #pragma unroll
        for (int kk = 0; kk < 4; ++kk) { fa[kk] = __int_as_float(ia[kk]); fb[kk] = __int_as_float(ib[kk]); }
        *(v4f*)&hl[8 * L]     = fa;
        *(v4f*)&hl[8 * L + 4] = fb;
      }
    }
    __syncthreads();  // B1: hl visible to all waves

    // --- all 16 waves: partial dots for their 4 gate rows ---
    v4f h0v = *(const v4f*)&hl[8 * L];
    v4f h1v = *(const v4f*)&hl[8 * L + 4];
    float hr[8] = {h0v[0], h0v[1], h0v[2], h0v[3], h1v[0], h1v[1], h1v[2], h1v[3]};
    float a4[4];
    #pragma unroll
    for (int j = 0; j < 4; ++j) {
      float a = 0.f;
      #pragma unroll
      for (int kk = 0; kk < 8; ++kk) a = fmaf(wreg[j][kk], hr[kk], a);
      a4[j] = row16_sum(a);
    }
    if ((L & 15) == 15) {
      int q = L >> 4;
      v4f rv = {a4[0], a4[1], a4[2], a4[3]};
      *(v4f*)&red2[w][q][0] = rv;
    }
    __syncthreads();  // B2: red2 complete

    if (w == 1) {
      // tail on wave1: gate row r=L; sum order bit-identical to r4/r9
      const int u = L & 15;
      const int ww = L >> 2, j = L & 3;
      const float sum = red2[ww][0][j] + red2[ww][1][j] + red2[ww][2][j] + red2[ww][3][j]
                      + xpl[s & 1][L];
      const float gv = ((L >> 4) == 2) ? tanhf(sum) : sigmoidf_(sum);
      const float ig = __shfl(gv, u);
      const float fg = __shfl(gv, u + 16);
      const float gg = __shfl(gv, u + 32);
      const float og = __shfl(gv, u + 48);
      if (L < 16) {
        cst = fg * cst + ig * gg;
        const float hval = og * tanhf(cst);
        float* hp = hsd + (size_t)t * HD + bb * 16 + L;
        asm volatile("global_store_dword %0, %1, off sc0 sc1" :: "v"(hp), "v"(hval) : "memory");
      }
    } else if (w == 2 && s + 1 < T_LEN) {
      const int tn = dir ? (t - 1) : (t + 1);
      xpl[(s + 1) & 1][L] = xp_sent_ld(xpd + (size_t)tn * G4 + xcol);
    }
  }
  __syncthreads();                       // drain all waves' final stores
  if (tid == 0) atomicAdd(&ctrl[0], 1);  // lstm-done counter (spin gate only)
}

// =========================================================
// fused gemm+lstm+spin kernel. 0..63 lstm, 64..575 gemm, 576..703 burn.
// gemm never waits; spin blocks gate nothing => no deadlock possible.
// =========================================================
__global__ __launch_bounds__(1024) void gemm_lstm_kernel(
    const float* __restrict__ sent, const float* __restrict__ h0,
    const float* __restrict__ c0,
    const float* __restrict__ wihf, const float* __restrict__ whhf,
    const float* __restrict__ bihf, const float* __restrict__ bhhf,
    const float* __restrict__ wihb, const float* __restrict__ whhb,
    const float* __restrict__ bihb, const float* __restrict__ bhhb,
    float* __restrict__ xp, float* __restrict__ hs, int* __restrict__ ctrl)
{
  const int b = blockIdx.x;
  if (b < 64)       lstm_role(b, h0, c0, whhf, whhb, xp, hs, ctrl);
  else if (b < 576) gemm_role(b - 64, sent, wihf, wihb, bihf, bhhf, bihb, bhhb, xp);
  else              spin_burn(&ctrl[0], 64u, 1 << 17);
}

// =========================================================
// feats[t][k] = [hs_f[t], hs_b[t]] . w_out[k] + b_out[k]   (r10 verbatim)
// =========================================================
__global__ __launch_bounds__(256) void feats_kernel(
    const float* __restrict__ hs, const float* __restrict__ wout,
    const float* __restrict__ bout, float* __restrict__ feats)
{
  __shared__ __align__(16) float xs[32][132];
  __shared__ __align__(16) float wl[34][132];
  const int tid = threadIdx.x;
  const int t0 = blockIdx.x * 32;
  const int m = tid & 31, ng = tid >> 5;
  float acc[5] = {0.f, 0.f, 0.f, 0.f, 0.f};
  for (int cc = 0; cc < 8; ++cc) {
    const int d = cc >> 2;
    const int c0 = (cc & 3) * 128;
    const float* hsrc = hs + (size_t)d * T_LEN * HD;
    const int wcol = d * HD + c0;
    __syncthreads();
    {
      const int row = tid >> 3, seg = tid & 7;
      const float* src = hsrc + (size_t)(t0 + row) * HD + c0 + seg * 16;
      #pragma unroll
      for (int i = 0; i < 4; ++i) {
        v4f v = *(const v4f*)(src + i * 4);
        *(v4f*)&xs[row][seg * 16 + i * 4] = v;
      }
    }
    for (int i = tid; i < 34 * 32; i += 256) {
      const int r = i >> 5, q = i & 31;
      v4f v = *(const v4f*)(wout + (size_t)r * E_DIM + wcol + q * 4);
      *(v4f*)&wl[r][q * 4] = v;
    }
    __syncthreads();
    for (int kq = 0; kq < 32; ++kq) {
      v4f xv = *(const v4f*)&xs[m][kq * 4];
      #pragma unroll
      for (int sl = 0; sl < 5; ++sl) {
        const int n = ng + sl * 8;
        if (n < K_TAGS) {
          v4f wv = *(const v4f*)&wl[n][kq * 4];
          acc[sl] = fmaf(xv[0], wv[0], acc[sl]);
          acc[sl] = fmaf(xv[1], wv[1], acc[sl]);
          acc[sl] = fmaf(xv[2], wv[2], acc[sl]);
          acc[sl] = fmaf(xv[3], wv[3], acc[sl]);
        }
      }
    }
  }
  #pragma unroll
  for (int sl = 0; sl < 5; ++sl) {
    const int n = ng + sl * 8;
    if (n < K_TAGS) feats[(size_t)(t0 + m) * K_TAGS + n] = acc[sl] + bout[n];
  }
}

// =========================================================
// Sequential Viterbi — block 0 = r10 verbatim (64-thread block, same
// codegen); blocks 1..256 = keep-clock burn until block 0 signals done.
// =========================================================
__global__ __launch_bounds__(64) void viterbi_kernel(
    const float* __restrict__ feats, const float* __restrict__ trans,
    float* __restrict__ d_out, int* __restrict__ bestlast,
    unsigned char* __restrict__ bp, int* __restrict__ ctrl)
{
  if (blockIdx.x != 0) { spin_burn(&ctrl[1], 1u, 1 << 15); return; }

  const int L = threadIdx.x;
  const int n = (L < K_TAGS) ? L : 0;
  const bool act = (L < K_TAGS);
  float tr[K_TAGS];
  #pragma unroll
  for (int p = 0; p < K_TAGS; ++p) tr[p] = trans[n * K_TAGS + p];
  const float tstop = trans[33 * K_TAGS + n];
  __shared__ float fvs[K_TAGS];
  if (act) fvs[n] = (n == 32) ? 0.f : -10000.f;
  asm volatile("s_waitcnt lgkmcnt(0)" ::: "memory");
  __builtin_amdgcn_sched_barrier(0);

  float feat_next = feats[n];
  float fvreg = 0.f;
  for (int t = 0; t < T_LEN; ++t) {
    const float feat = feat_next;
    if (t + 1 < T_LEN) feat_next = feats[(size_t)(t + 1) * K_TAGS + n];
    float val[K_TAGS];
    int   idx[K_TAGS];
    #pragma unroll
    for (int p = 0; p < K_TAGS; ++p) { val[p] = fvs[p] + tr[p]; idx[p] = p; }
    // ordered tree; right wins only if strictly greater => first-max
    #pragma unroll
    for (int st = 1; st < K_TAGS; st <<= 1) {
      #pragma unroll
      for (int i = 0; i + st < K_TAGS; i += 2 * st) {
        if (val[i + st] > val[i]) { val[i] = val[i + st]; idx[i] = idx[i + st]; }
      }
    }
    fvreg = val[0] + feat;
    if (act) {
      bp[(size_t)t * K_TAGS + n] = (unsigned char)idx[0];
      fvs[n] = fvreg;
    }
    asm volatile("s_waitcnt lgkmcnt(0)" ::: "memory");
    __builtin_amdgcn_sched_barrier(0);
  }
  if (act) fvs[n] = fvreg + tstop;      // terminal scores
  asm volatile("s_waitcnt lgkmcnt(0)" ::: "memory");
  __builtin_amdgcn_sched_barrier(0);
  if (L == 0) {
    float best = -3.4e38f; int bi = 0;
    for (int k = 0; k < K_TAGS; ++k) {
      const float v = fvs[k];
      if (v > best) { best = v; bi = k; }
    }
    d_out[0] = best;
    *bestlast = bi;
    int one = 1;
    int* fp = &ctrl[1];
    asm volatile("global_store_dword %0, %1, off sc0 sc1" :: "v"(fp), "v"(one) : "memory");
  }
}

// =========================================================
// Parallel backtrace: 128 chunks of 64 steps (r10 verbatim).
// =========================================================
__global__ __launch_bounds__(1024) void backtrace_kernel(
    const unsigned char* __restrict__ bp, const int* __restrict__ bestlast,
    float* __restrict__ d_out)
{
  __shared__ unsigned char exitl[128 * K_TAGS];
  __shared__ unsigned char entl[128];
  const int tid = threadIdx.x;
  for (int W = tid; W < 128 * K_TAGS; W += 1024) {
    const int c = W / K_TAGS;
    int tg = W % K_TAGS;
    for (int t = c * 64 + 63; t >= c * 64; --t) tg = bp[(size_t)t * K_TAGS + tg];
    exitl[W] = (unsigned char)tg;
  }
  __syncthreads();
  if (tid == 0) {
    int tag = *bestlast;
    entl[127] = (unsigned char)tag;
    for (int c = 127; c >= 1; --c) {
      tag = exitl[c * K_TAGS + tag];
      entl[c - 1] = (unsigned char)tag;
    }
  }
  __syncthreads();
  if (tid < 128) {
    const int c = tid;
    int tg = entl[c];
    for (int t = c * 64 + 63; t >= c * 64; --t) {
      d_out[1 + t] = (float)tg;
      tg = bp[(size_t)t * K_TAGS + tg];
    }
  }
}

// =========================================================
extern "C" void kernel_launch(void* const* d_in, const int* in_sizes, int n_in,
                              void* d_out, int out_size, void* d_ws, size_t ws_size,
                              hipStream_t stream)
{
  const float* sent = (const float*)d_in[0];
  const float* h0   = (const float*)d_in[1];
  const float* c0   = (const float*)d_in[2];
  const float* wihf = (const float*)d_in[3];
  const float* whhf = (const float*)d_in[4];
  const float* bihf = (const float*)d_in[5];
  const float* bhhf = (const float*)d_in[6];
  const float* wihb = (const float*)d_in[7];
  const float* whhb = (const float*)d_in[8];
  const float* bihb = (const float*)d_in[9];
  const float* bhhb = (const float*)d_in[10];
  const float* wout = (const float*)d_in[11];
  const float* bout = (const float*)d_in[12];
  const float* trans = (const float*)d_in[13];

  float* out = (float*)d_out;
  char* ws = (char*)d_ws;
  float* xp    = (float*)(ws + XP_OFF);
  float* hs    = (float*)(ws + HS_OFF);
  float* feats = (float*)(ws + FEATS_OFF);
  unsigned char* bp = (unsigned char*)(ws + BP_OFF);
  int* ctrl     = (int*)(ws + CTRL_OFF);
  int* bestlast = (int*)(ws + BEST_OFF);

  // sentinels + control reset every call (deterministic replays)
  hipMemsetAsync(xp,   0xFF, (size_t)2 * T_LEN * G4 * sizeof(float), stream);
  hipMemsetAsync(hs,   0xFF, (size_t)2 * T_LEN * HD * sizeof(float), stream);
  hipMemsetAsync(ctrl, 0,    16 * sizeof(int), stream);

  // sentence passthrough output
  hipMemcpyAsync(out + 1 + T_LEN, sent, (size_t)T_LEN * E_DIM * sizeof(float),
                 hipMemcpyDeviceToDevice, stream);

  gemm_lstm_kernel<<<704, 1024, 0, stream>>>(
      sent, h0, c0, wihf, whhf, bihf, bhhf, wihb, whhb, bihb, bhhb, xp, hs, ctrl);

  feats_kernel<<<T_LEN / 32, 256, 0, stream>>>(hs, wout, bout, feats);

  viterbi_kernel<<<257, 64, 0, stream>>>(feats, trans, out, bestlast, bp, ctrl);

  backtrace_kernel<<<1, 1024, 0, stream>>>(bp, bestlast, out);
}